// Round 4
// baseline (177.261 us; speedup 1.0000x reference)
//
#include <hip/hip_runtime.h>
#include <math.h>

#define HF 96
#define WF 160
#define CH 100
#define HH 48      // HF/2
#define HW 80      // WF/2
#define NPIX 3840  // HH*HW
#define MD 9
#define KD 19
#define K2 361
#define NMAX 8

// ws float offsets (same 2,161,920-float footprint as R1, known to fit).
// Deliberate overlap-guards: OOB-masked reads off Yt/ys edges land in the
// neighboring arrays (values unused — mask selects 1.0), so no extra pad.
#define OFF_XT 0
#define OFF_YT (CH*NPIX)               // 384000
#define OFF_XS (2*CH*NPIX)             // 768000
#define OFF_YS (2*CH*NPIX + NPIX)      // 771840
#define OFF_DH (2*CH*NPIX + 2*NPIX)    // 775680  (k-major: [K2][NPIX])

// ---------------- Kernel A: pool + norms, channel-major outputs ----------------
__global__ __launch_bounds__(128) void pool_kernel(
    const float* __restrict__ q, const float* __restrict__ p,
    float* __restrict__ Xt, float* __restrict__ Yt,
    float* __restrict__ xs, float* __restrict__ ys) {
  int pix = blockIdx.x;
  int i = pix / HW, j = pix % HW;
  int c = threadIdx.x;
  __shared__ float red[2][128];
  float xv = 0.f, yv = 0.f;
  if (c < CH) {
    int base = (2 * i) * WF * CH + (2 * j) * CH + c;
    xv = 0.25f * (q[base] + q[base + CH] + q[base + WF * CH] + q[base + WF * CH + CH]);
    yv = 0.25f * (p[base] + p[base + CH] + p[base + WF * CH] + p[base + WF * CH + CH]);
    Xt[c * NPIX + pix] = xv;
    Yt[c * NPIX + pix] = yv;
  }
  red[0][c] = xv * xv;
  red[1][c] = yv * yv;
  __syncthreads();
  for (int s = 64; s > 0; s >>= 1) {
    if (c < s) { red[0][c] += red[0][c + s]; red[1][c] += red[1][c + s]; }
    __syncthreads();
  }
  if (c == 0) { xs[pix] = red[0][0]; ys[pix] = red[1][0]; }
}

// ---------------- Kernel B: pure-register local correlation ----------------
// Thread = (pixel, dy, dx-half). Owns acc[10] (dx = 10h .. 10h+9; h=1 keeps 9).
// Lanes = consecutive pixels -> all global loads coalesced; L1 serves the
// sliding y-window. No LDS, no cross-thread reduction.
// Grid: x = 15 strips of 256 px, y = 38 (u = dy*2 + h). 145,920 threads.
__global__ __launch_bounds__(256) void dist_kernel(
    const float* __restrict__ Xt, const float* __restrict__ Yt,
    const float* __restrict__ xs, const float* __restrict__ ys,
    float* __restrict__ dh2) {
  int pix = blockIdx.x * 256 + threadIdx.x;
  int u = blockIdx.y;
  int dy = u >> 1, h = u & 1;
  int i = pix / HW, j = pix - i * HW;
  int row = i + dy - MD;
  bool rowOK = (row >= 0 && row < HH);
  int rcl = row < 0 ? 0 : (row > HH - 1 ? HH - 1 : row);
  int cbase = j - MD + 10 * h;          // global dx-col for d=0

  float acc[10];
#pragma unroll
  for (int d = 0; d < 10; ++d) acc[d] = 0.f;

  const float* xp = Xt + pix;
  const float* yp = Yt + rcl * HW + cbase;   // may stray <=9/<=17 floats OOB: lands
                                             // in Xt tail / xs head, value masked.
  for (int c = 0; c < CH; ++c) {
    float xv = *xp;
#pragma unroll
    for (int d = 0; d < 10; ++d)
      acc[d] = fmaf(xv, yp[d], acc[d]);
    xp += NPIX; yp += NPIX;
  }

  float xss = xs[pix];
  const float* ysr = ys + rcl * HW;
  int nd = h ? 9 : 10;
  int kbase = dy * KD + 10 * h;
#pragma unroll
  for (int d = 0; d < 10; ++d) {
    if (d >= nd) break;
    int jj = cbase + d;
    bool ok = rowOK && (jj >= 0) && (jj < HW);
    int jcl = jj < 0 ? 0 : (jj > HW - 1 ? HW - 1 : jj);
    float s = xss + ysr[jcl] - 2.f * acc[d];
    float e = __expf(-s);
    float r = ok ? (1.f - e) / (1.f + e) : 1.0f;
    dh2[(kbase + d) * NPIX + pix] = r;   // lanes = consecutive pix: coalesced
  }
}

// ---------------- Kernel C: bilinear upsample + masked min (k-major dh) -------
// Block = 256 thr = 4 waves; all 4 waves cover the SAME 64 consecutive full-res
// pixels, splitting k 4 ways; LDS min-combine. Grid = 240 blocks.
__global__ __launch_bounds__(256) void upmin_kernel(
    const float* __restrict__ dh2, const int* __restrict__ labels,
    const int* __restrict__ gt, int n, float* __restrict__ out) {
  int w = threadIdx.x >> 6;
  int lane = threadIdx.x & 63;
  int pixel = blockIdx.x * 64 + lane;
  int I = pixel / WF, J = pixel - I * WF;

  const float sy = (float)((HH - 1.0) / (HF - 1.0));
  const float sx = (float)((HW - 1.0) / (WF - 1.0));
  float py = (float)I * sy;
  int y0 = (int)floorf(py); if (y0 > HH - 2) y0 = HH - 2; if (y0 < 0) y0 = 0;
  float fy = py - (float)y0;
  float px = (float)J * sx;
  int x0 = (int)floorf(px); if (x0 > HW - 2) x0 = HW - 2; if (x0 < 0) x0 = 0;
  float fx = px - (float)x0;
  float w00 = (1.f - fy) * (1.f - fx), w01 = (1.f - fy) * fx;
  float w10 = fy * (1.f - fx),         w11 = fy * fx;
  int np00 = y0 * HW + x0;

  int gtl[NMAX];
  for (int o = 0; o < n; ++o) gtl[o] = gt[o];
  float mins[NMAX];
#pragma unroll
  for (int o = 0; o < NMAX; ++o) mins[o] = 1.0f;

  for (int k = w; k < K2; k += 4) {
    int dy = k / KD, dx = k - dy * KD;
    int P = I + dy - MD, Q = J + dx - MD;
    const float* dk = dh2 + k * NPIX + np00;
    float v = w00 * dk[0] + w01 * dk[1] + w10 * dk[HW] + w11 * dk[HW + 1];
    if (P >= 0 && P < HF && Q >= 0 && Q < WF) {
      int lab = labels[P * WF + Q];
      for (int o = 0; o < n; ++o)
        if (lab == gtl[o]) mins[o] = fminf(mins[o], v);
    }
  }

  __shared__ float mm[4][64][NMAX];
  for (int o = 0; o < n; ++o) mm[w][lane][o] = mins[o];
  __syncthreads();
  if (w == 0) {
    for (int o = 0; o < n; ++o) {
      float m = fminf(fminf(mm[0][lane][o], mm[1][lane][o]),
                      fminf(mm[2][lane][o], mm[3][lane][o]));
      out[pixel * n + o] = m;
    }
  }
}

extern "C" void kernel_launch(void* const* d_in, const int* in_sizes, int n_in,
                              void* d_out, int out_size, void* d_ws, size_t ws_size,
                              hipStream_t stream) {
  const float* prev  = (const float*)d_in[0];   // prev_frame_embedding -> y
  const float* query = (const float*)d_in[1];   // query_embedding      -> x
  const int* labels  = (const int*)d_in[2];
  const int* gt      = (const int*)d_in[3];
  int n = in_sizes[3];
  if (n > NMAX) n = NMAX;
  float* ws = (float*)d_ws;
  float* Xt = ws + OFF_XT;
  float* Yt = ws + OFF_YT;
  float* xs = ws + OFF_XS;
  float* ys = ws + OFF_YS;
  float* dh2 = ws + OFF_DH;
  float* out = (float*)d_out;

  hipLaunchKernelGGL(pool_kernel, dim3(NPIX), dim3(128), 0, stream,
                     query, prev, Xt, Yt, xs, ys);
  hipLaunchKernelGGL(dist_kernel, dim3(15, 38), dim3(256), 0, stream,
                     Xt, Yt, xs, ys, dh2);
  hipLaunchKernelGGL(upmin_kernel, dim3(HF * WF / 64), dim3(256), 0, stream,
                     dh2, labels, gt, n, out);
}

// Round 5
// 120.819 us; speedup vs baseline: 1.4672x; 1.4672x over previous
//
#include <hip/hip_runtime.h>
#include <math.h>

#define HF 96
#define WF 160
#define CH 100
#define HH 48      // HF/2
#define HW 80      // WF/2
#define NPIX 3840  // HH*HW
#define MD 9
#define KD 19
#define K2 361
#define NMAX 8

// ws float offsets. Deliberate overlap-guards: OOB-masked reads off Yt/ys edges
// land in the neighboring arrays (values unused — mask selects 1.0).
#define OFF_XT 0
#define OFF_YT (CH*NPIX)               // 384000
#define OFF_XS (2*CH*NPIX)             // 768000
#define OFF_YS (2*CH*NPIX + NPIX)      // 771840
#define OFF_DH (2*CH*NPIX + 2*NPIX)    // 775680  (k-major: [K2][NPIX])

// ---------------- Kernel A: pool + norms, channel-major outputs ----------------
__global__ __launch_bounds__(128) void pool_kernel(
    const float* __restrict__ q, const float* __restrict__ p,
    float* __restrict__ Xt, float* __restrict__ Yt,
    float* __restrict__ xs, float* __restrict__ ys) {
  int pix = blockIdx.x;
  int i = pix / HW, j = pix % HW;
  int c = threadIdx.x;
  __shared__ float red[2][128];
  float xv = 0.f, yv = 0.f;
  if (c < CH) {
    int base = (2 * i) * WF * CH + (2 * j) * CH + c;
    xv = 0.25f * (q[base] + q[base + CH] + q[base + WF * CH] + q[base + WF * CH + CH]);
    yv = 0.25f * (p[base] + p[base + CH] + p[base + WF * CH] + p[base + WF * CH + CH]);
    Xt[c * NPIX + pix] = xv;
    Yt[c * NPIX + pix] = yv;
  }
  red[0][c] = xv * xv;
  red[1][c] = yv * yv;
  __syncthreads();
  for (int s = 64; s > 0; s >>= 1) {
    if (c < s) { red[0][c] += red[0][c + s]; red[1][c] += red[1][c + s]; }
    __syncthreads();
  }
  if (c == 0) { xs[pix] = red[0][0]; ys[pix] = red[1][0]; }
}

// ---------------- Kernel B: pure-register local correlation ----------------
// Thread = (pixel, dy, dx-half). Owns acc[10] in registers; lanes = consecutive
// pixels -> all global loads coalesced. No LDS, no cross-thread reduction.
__global__ __launch_bounds__(256) void dist_kernel(
    const float* __restrict__ Xt, const float* __restrict__ Yt,
    const float* __restrict__ xs, const float* __restrict__ ys,
    float* __restrict__ dh2) {
  int pix = blockIdx.x * 256 + threadIdx.x;
  int u = blockIdx.y;
  int dy = u >> 1, h = u & 1;
  int i = pix / HW, j = pix - i * HW;
  int row = i + dy - MD;
  bool rowOK = (row >= 0 && row < HH);
  int rcl = row < 0 ? 0 : (row > HH - 1 ? HH - 1 : row);
  int cbase = j - MD + 10 * h;

  float acc[10];
#pragma unroll
  for (int d = 0; d < 10; ++d) acc[d] = 0.f;

  const float* xp = Xt + pix;
  const float* yp = Yt + rcl * HW + cbase;   // may stray <=17 floats OOB: lands
                                             // in adjacent ws array, value masked.
  for (int c = 0; c < CH; ++c) {
    float xv = *xp;
#pragma unroll
    for (int d = 0; d < 10; ++d)
      acc[d] = fmaf(xv, yp[d], acc[d]);
    xp += NPIX; yp += NPIX;
  }

  float xss = xs[pix];
  const float* ysr = ys + rcl * HW;
  int nd = h ? 9 : 10;
  int kbase = dy * KD + 10 * h;
#pragma unroll
  for (int d = 0; d < 10; ++d) {
    if (d >= nd) break;
    int jj = cbase + d;
    bool ok = rowOK && (jj >= 0) && (jj < HW);
    int jcl = jj < 0 ? 0 : (jj > HW - 1 ? HW - 1 : jj);
    float s = xss + ysr[jcl] - 2.f * acc[d];
    float e = __expf(-s);
    float r = ok ? (1.f - e) / (1.f + e) : 1.0f;
    dh2[(kbase + d) * NPIX + pix] = r;
  }
}

// ---------------- Kernel C: bilinear upsample + masked min (k-major dh) -------
// Templated on N so mins[]/gtl[] live in registers (runtime-n arrays demoted to
// scratch: R4 showed VGPR=20 + 70us). Block = 1024 thr = 16 waves over the SAME
// 64 pixels, k split 16 ways; LDS min-combine. Grid = 240 blocks.
template <int N>
__global__ __launch_bounds__(1024) void upmin_kernel(
    const float* __restrict__ dh2, const int* __restrict__ labels,
    const int* __restrict__ gt, float* __restrict__ out) {
  int w = threadIdx.x >> 6;        // 0..15: k-slice
  int lane = threadIdx.x & 63;     // pixel within strip
  int pixel = blockIdx.x * 64 + lane;
  int I = pixel / WF, J = pixel - I * WF;

  const float sy = (float)((HH - 1.0) / (HF - 1.0));
  const float sx = (float)((HW - 1.0) / (WF - 1.0));
  float py = (float)I * sy;
  int y0 = (int)floorf(py); if (y0 > HH - 2) y0 = HH - 2; if (y0 < 0) y0 = 0;
  float fy = py - (float)y0;
  float px = (float)J * sx;
  int x0 = (int)floorf(px); if (x0 > HW - 2) x0 = HW - 2; if (x0 < 0) x0 = 0;
  float fx = px - (float)x0;
  float w00 = (1.f - fy) * (1.f - fx), w01 = (1.f - fy) * fx;
  float w10 = fy * (1.f - fx),         w11 = fy * fx;
  int np00 = y0 * HW + x0;

  int gtl[N];
  float mins[N];
#pragma unroll
  for (int o = 0; o < N; ++o) { gtl[o] = gt[o]; mins[o] = 1.0f; }

  for (int k = w; k < K2; k += 16) {
    int dy = k / KD, dx = k - dy * KD;
    int P = I + dy - MD, Q = J + dx - MD;
    const float* dk = dh2 + k * NPIX + np00;
    float v = w00 * dk[0] + w01 * dk[1] + w10 * dk[HW] + w11 * dk[HW + 1];
    if (P >= 0 && P < HF && Q >= 0 && Q < WF) {
      int lab = labels[P * WF + Q];
#pragma unroll
      for (int o = 0; o < N; ++o)
        if (lab == gtl[o]) mins[o] = fminf(mins[o], v);
    }
  }

  __shared__ float mm[16][64][N];
#pragma unroll
  for (int o = 0; o < N; ++o) mm[w][lane][o] = mins[o];
  __syncthreads();
  if (w < 8) {
#pragma unroll
    for (int o = 0; o < N; ++o)
      mm[w][lane][o] = fminf(mm[w][lane][o], mm[w + 8][lane][o]);
  }
  __syncthreads();
  if (w < 4) {
#pragma unroll
    for (int o = 0; o < N; ++o)
      mm[w][lane][o] = fminf(mm[w][lane][o], mm[w + 4][lane][o]);
  }
  __syncthreads();
  if (w == 0) {
#pragma unroll
    for (int o = 0; o < N; ++o) {
      float m = fminf(fminf(mm[0][lane][o], mm[1][lane][o]),
                      fminf(mm[2][lane][o], mm[3][lane][o]));
      out[pixel * N + o] = m;
    }
  }
}

extern "C" void kernel_launch(void* const* d_in, const int* in_sizes, int n_in,
                              void* d_out, int out_size, void* d_ws, size_t ws_size,
                              hipStream_t stream) {
  const float* prev  = (const float*)d_in[0];   // prev_frame_embedding -> y
  const float* query = (const float*)d_in[1];   // query_embedding      -> x
  const int* labels  = (const int*)d_in[2];
  const int* gt      = (const int*)d_in[3];
  int n = in_sizes[3];
  if (n > NMAX) n = NMAX;
  float* ws = (float*)d_ws;
  float* Xt = ws + OFF_XT;
  float* Yt = ws + OFF_YT;
  float* xs = ws + OFF_XS;
  float* ys = ws + OFF_YS;
  float* dh2 = ws + OFF_DH;
  float* out = (float*)d_out;

  hipLaunchKernelGGL(pool_kernel, dim3(NPIX), dim3(128), 0, stream,
                     query, prev, Xt, Yt, xs, ys);
  hipLaunchKernelGGL(dist_kernel, dim3(15, 38), dim3(256), 0, stream,
                     Xt, Yt, xs, ys, dh2);
  dim3 ug(HF * WF / 64), ub(1024);
  switch (n) {
    case 1: hipLaunchKernelGGL(upmin_kernel<1>, ug, ub, 0, stream, dh2, labels, gt, out); break;
    case 2: hipLaunchKernelGGL(upmin_kernel<2>, ug, ub, 0, stream, dh2, labels, gt, out); break;
    case 3: hipLaunchKernelGGL(upmin_kernel<3>, ug, ub, 0, stream, dh2, labels, gt, out); break;
    case 4: hipLaunchKernelGGL(upmin_kernel<4>, ug, ub, 0, stream, dh2, labels, gt, out); break;
    case 5: hipLaunchKernelGGL(upmin_kernel<5>, ug, ub, 0, stream, dh2, labels, gt, out); break;
    case 6: hipLaunchKernelGGL(upmin_kernel<6>, ug, ub, 0, stream, dh2, labels, gt, out); break;
    case 7: hipLaunchKernelGGL(upmin_kernel<7>, ug, ub, 0, stream, dh2, labels, gt, out); break;
    default: hipLaunchKernelGGL(upmin_kernel<8>, ug, ub, 0, stream, dh2, labels, gt, out); break;
  }
}

// Round 6
// 119.421 us; speedup vs baseline: 1.4843x; 1.0117x over previous
//
#include <hip/hip_runtime.h>
#include <hip/hip_bf16.h>
#include <math.h>

#define HF 96
#define WF 160
#define CH 100
#define HH 48      // HF/2
#define HW 80      // WF/2
#define NPIX 3840  // HH*HW
#define MD 9
#define KD 19
#define K2 361
#define NMAX 8

// ws float offsets. Deliberate overlap-guards: OOB-masked reads off Yt/ys edges
// land in the neighboring arrays (values unused — mask selects 1.0).
#define OFF_XT 0
#define OFF_YT (CH*NPIX)               // 384000
#define OFF_XS (2*CH*NPIX)             // 768000
#define OFF_YS (2*CH*NPIX + NPIX)      // 771840
#define OFF_DH (2*CH*NPIX + 2*NPIX)    // 775680  (bf16, k-major: [K2][NPIX])

// ---------------- Kernel A: pool + norms, channel-major, shuffle-reduced ------
// 4 waves/block, one half-res pixel per wave, no barriers. Grid = 960.
__global__ __launch_bounds__(256) void pool_kernel(
    const float* __restrict__ q, const float* __restrict__ p,
    float* __restrict__ Xt, float* __restrict__ Yt,
    float* __restrict__ xs, float* __restrict__ ys) {
  int w = threadIdx.x >> 6, L = threadIdx.x & 63;
  int pix = blockIdx.x * 4 + w;
  int i = pix / HW, j = pix - i * HW;
  int base = (2 * i) * WF * CH + (2 * j) * CH;
  float nx = 0.f, ny = 0.f;
  for (int c = L; c < CH; c += 64) {
    int b = base + c;
    float xv = 0.25f * (q[b] + q[b + CH] + q[b + WF * CH] + q[b + WF * CH + CH]);
    float yv = 0.25f * (p[b] + p[b + CH] + p[b + WF * CH] + p[b + WF * CH + CH]);
    Xt[c * NPIX + pix] = xv;
    Yt[c * NPIX + pix] = yv;
    nx = fmaf(xv, xv, nx);
    ny = fmaf(yv, yv, ny);
  }
  for (int s = 32; s > 0; s >>= 1) {
    nx += __shfl_down(nx, s);
    ny += __shfl_down(ny, s);
  }
  if (L == 0) { xs[pix] = nx; ys[pix] = ny; }
}

// ---------------- Kernel B: pure-register local correlation ----------------
// Thread = (pixel, dy, dx-half). acc[10] in registers; lanes = consecutive
// pixels -> coalesced. No LDS. Stores bf16 (halved write traffic).
__global__ __launch_bounds__(256) void dist_kernel(
    const float* __restrict__ Xt, const float* __restrict__ Yt,
    const float* __restrict__ xs, const float* __restrict__ ys,
    __hip_bfloat16* __restrict__ dh2) {
  int pix = blockIdx.x * 256 + threadIdx.x;
  int u = blockIdx.y;
  int dy = u >> 1, h = u & 1;
  int i = pix / HW, j = pix - i * HW;
  int row = i + dy - MD;
  bool rowOK = (row >= 0 && row < HH);
  int rcl = row < 0 ? 0 : (row > HH - 1 ? HH - 1 : row);
  int cbase = j - MD + 10 * h;

  float acc[10];
#pragma unroll
  for (int d = 0; d < 10; ++d) acc[d] = 0.f;

  const float* xp = Xt + pix;
  const float* yp = Yt + rcl * HW + cbase;   // may stray <=17 floats OOB: lands
                                             // in adjacent ws array, value masked.
  for (int c = 0; c < CH; ++c) {
    float xv = *xp;
#pragma unroll
    for (int d = 0; d < 10; ++d)
      acc[d] = fmaf(xv, yp[d], acc[d]);
    xp += NPIX; yp += NPIX;
  }

  float xss = xs[pix];
  const float* ysr = ys + rcl * HW;
  int nd = h ? 9 : 10;
  int kbase = dy * KD + 10 * h;
#pragma unroll
  for (int d = 0; d < 10; ++d) {
    if (d >= nd) break;
    int jj = cbase + d;
    bool ok = rowOK && (jj >= 0) && (jj < HW);
    int jcl = jj < 0 ? 0 : (jj > HW - 1 ? HW - 1 : jj);
    float s = xss + ysr[jcl] - 2.f * acc[d];
    float e = __expf(-s);
    float r = ok ? (1.f - e) / (1.f + e) : 1.0f;
    dh2[(kbase + d) * NPIX + pix] = __float2bfloat16(r);
  }
}

// ---------------- Kernel C: bilinear upsample + masked min (bf16, k-major) ----
// Templated on N (runtime-n arrays demote to scratch: R4, VGPR=20, 70us).
// Block = 1024 thr = 16 waves over the SAME 64 pixels, k split 16 ways;
// LDS min-combine. Grid = 240 blocks.
template <int N>
__global__ __launch_bounds__(1024) void upmin_kernel(
    const __hip_bfloat16* __restrict__ dh2, const int* __restrict__ labels,
    const int* __restrict__ gt, float* __restrict__ out) {
  int w = threadIdx.x >> 6;        // 0..15: k-slice
  int lane = threadIdx.x & 63;     // pixel within strip
  int pixel = blockIdx.x * 64 + lane;
  int I = pixel / WF, J = pixel - I * WF;

  const float sy = (float)((HH - 1.0) / (HF - 1.0));
  const float sx = (float)((HW - 1.0) / (WF - 1.0));
  float py = (float)I * sy;
  int y0 = (int)floorf(py); if (y0 > HH - 2) y0 = HH - 2; if (y0 < 0) y0 = 0;
  float fy = py - (float)y0;
  float px = (float)J * sx;
  int x0 = (int)floorf(px); if (x0 > HW - 2) x0 = HW - 2; if (x0 < 0) x0 = 0;
  float fx = px - (float)x0;
  float w00 = (1.f - fy) * (1.f - fx), w01 = (1.f - fy) * fx;
  float w10 = fy * (1.f - fx),         w11 = fy * fx;
  int np00 = y0 * HW + x0;

  int gtl[N];
  float mins[N];
#pragma unroll
  for (int o = 0; o < N; ++o) { gtl[o] = gt[o]; mins[o] = 1.0f; }

  for (int k = w; k < K2; k += 16) {
    int dy = k / KD, dx = k - dy * KD;
    int P = I + dy - MD, Q = J + dx - MD;
    const __hip_bfloat16* dk = dh2 + k * NPIX + np00;
    float v = w00 * __bfloat162float(dk[0]) + w01 * __bfloat162float(dk[1]) +
              w10 * __bfloat162float(dk[HW]) + w11 * __bfloat162float(dk[HW + 1]);
    if (P >= 0 && P < HF && Q >= 0 && Q < WF) {
      int lab = labels[P * WF + Q];
#pragma unroll
      for (int o = 0; o < N; ++o)
        if (lab == gtl[o]) mins[o] = fminf(mins[o], v);
    }
  }

  __shared__ float mm[16][64][N];
#pragma unroll
  for (int o = 0; o < N; ++o) mm[w][lane][o] = mins[o];
  __syncthreads();
  if (w < 8) {
#pragma unroll
    for (int o = 0; o < N; ++o)
      mm[w][lane][o] = fminf(mm[w][lane][o], mm[w + 8][lane][o]);
  }
  __syncthreads();
  if (w < 4) {
#pragma unroll
    for (int o = 0; o < N; ++o)
      mm[w][lane][o] = fminf(mm[w][lane][o], mm[w + 4][lane][o]);
  }
  __syncthreads();
  if (w == 0) {
#pragma unroll
    for (int o = 0; o < N; ++o) {
      float m = fminf(fminf(mm[0][lane][o], mm[1][lane][o]),
                      fminf(mm[2][lane][o], mm[3][lane][o]));
      out[pixel * N + o] = m;
    }
  }
}

extern "C" void kernel_launch(void* const* d_in, const int* in_sizes, int n_in,
                              void* d_out, int out_size, void* d_ws, size_t ws_size,
                              hipStream_t stream) {
  const float* prev  = (const float*)d_in[0];   // prev_frame_embedding -> y
  const float* query = (const float*)d_in[1];   // query_embedding      -> x
  const int* labels  = (const int*)d_in[2];
  const int* gt      = (const int*)d_in[3];
  int n = in_sizes[3];
  if (n > NMAX) n = NMAX;
  float* ws = (float*)d_ws;
  float* Xt = ws + OFF_XT;
  float* Yt = ws + OFF_YT;
  float* xs = ws + OFF_XS;
  float* ys = ws + OFF_YS;
  __hip_bfloat16* dh2 = (__hip_bfloat16*)(ws + OFF_DH);
  float* out = (float*)d_out;

  hipLaunchKernelGGL(pool_kernel, dim3(NPIX / 4), dim3(256), 0, stream,
                     query, prev, Xt, Yt, xs, ys);
  hipLaunchKernelGGL(dist_kernel, dim3(15, 38), dim3(256), 0, stream,
                     Xt, Yt, xs, ys, dh2);
  dim3 ug(HF * WF / 64), ub(1024);
  switch (n) {
    case 1: hipLaunchKernelGGL(upmin_kernel<1>, ug, ub, 0, stream, dh2, labels, gt, out); break;
    case 2: hipLaunchKernelGGL(upmin_kernel<2>, ug, ub, 0, stream, dh2, labels, gt, out); break;
    case 3: hipLaunchKernelGGL(upmin_kernel<3>, ug, ub, 0, stream, dh2, labels, gt, out); break;
    case 4: hipLaunchKernelGGL(upmin_kernel<4>, ug, ub, 0, stream, dh2, labels, gt, out); break;
    case 5: hipLaunchKernelGGL(upmin_kernel<5>, ug, ub, 0, stream, dh2, labels, gt, out); break;
    case 6: hipLaunchKernelGGL(upmin_kernel<6>, ug, ub, 0, stream, dh2, labels, gt, out); break;
    case 7: hipLaunchKernelGGL(upmin_kernel<7>, ug, ub, 0, stream, dh2, labels, gt, out); break;
    default: hipLaunchKernelGGL(upmin_kernel<8>, ug, ub, 0, stream, dh2, labels, gt, out); break;
  }
}